// Round 2
// baseline (352.934 us; speedup 1.0000x reference)
//
#include <hip/hip_runtime.h>

#define N_NODES 50000
#define E_EDGES 800000
#define D_INF   128
#define D_HIDF  512
#define D_OUTF  128
#define SCAN_NB ((N_NODES + 255) / 256)   // 196 blocks
#define G2BLKS  ((N_NODES + 63) / 64)     // 782 row-blocks for both GEMMs (64-row tiles)
#define EQ      (E_EDGES / 4)             // 200,000 edges per ILP slot

typedef unsigned short u16;
typedef __attribute__((ext_vector_type(8))) short short8;
typedef __attribute__((ext_vector_type(4))) float floatx4;

__device__ __forceinline__ u16 f2bf(float f) {
    union { float f; unsigned u; } v; v.f = f;
    unsigned r = (v.u + 0x7fffu + ((v.u >> 16) & 1u)) >> 16;
    return (u16)r;
}
__device__ __forceinline__ float bf2f(u16 b) {
    union { unsigned u; float f; } v; v.u = ((unsigned)b) << 16; return v.f;
}

// ---------------- cast v -> bf16 ----------------
__global__ void cast_v_kernel(const float* __restrict__ v, u16* __restrict__ vbf) {
    int i = blockIdx.x * blockDim.x + threadIdx.x;
    if (i >= N_NODES * D_INF / 8) return;
    const float4 a = ((const float4*)v)[i * 2];
    const float4 b = ((const float4*)v)[i * 2 + 1];
    u16 o[8];
    o[0] = f2bf(a.x); o[1] = f2bf(a.y); o[2] = f2bf(a.z); o[3] = f2bf(a.w);
    o[4] = f2bf(b.x); o[5] = f2bf(b.y); o[6] = f2bf(b.z); o[7] = f2bf(b.w);
    ((float4*)vbf)[i] = *(const float4*)o;
}

// ---------------- hist + per-edge pos ----------------
__global__ void hist_kernel(const int* __restrict__ dst, int* __restrict__ counts,
                            int* __restrict__ pos) {
    int t = blockIdx.x * blockDim.x + threadIdx.x;
    if (t >= EQ) return;
    int d0 = dst[t];
    int d1 = dst[t + EQ];
    int d2 = dst[t + 2 * EQ];
    int d3 = dst[t + 3 * EQ];
    int p0 = atomicAdd(&counts[d0], 1);
    int p1 = atomicAdd(&counts[d1], 1);
    int p2 = atomicAdd(&counts[d2], 1);
    int p3 = atomicAdd(&counts[d3], 1);
    pos[t]          = p0;
    pos[t + EQ]     = p1;
    pos[t + 2 * EQ] = p2;
    pos[t + 3 * EQ] = p3;
}

// ---------------- weight prep: W1 transpose early ----------------
__global__ void prep_w1_kernel(const float* __restrict__ W1, u16* __restrict__ W1t) {
    int idx = blockIdx.x * blockDim.x + threadIdx.x;
    if (idx >= 128 * 512) return;
    int k1 = idx >> 9, n1 = idx & 511;      // W1 [128][512]
    W1t[n1 * 128 + k1] = f2bf(W1[idx]);
}

// ---- W2 transpose with BN1 scale folded into its rows (after bn_finalize1) ----
__global__ void prep_w2_kernel(const float* __restrict__ W2, const float* __restrict__ scale1,
                               u16* __restrict__ W2t) {
    int idx = blockIdx.x * blockDim.x + threadIdx.x;
    if (idx >= 512 * 128) return;
    int k2 = idx >> 7, n2 = idx & 127;      // W2 [512][128]
    W2t[n2 * 512 + k2] = f2bf(W2[idx] * scale1[k2]);
}

// ---------------- scan phase 1: per-block sums ----------------
__global__ __launch_bounds__(256) void reduce_kernel(const int* __restrict__ counts,
                                                     int* __restrict__ block_sums) {
    __shared__ int lsum[4];
    int tid = threadIdx.x;
    int gid = blockIdx.x * 256 + tid;
    int s = (gid < N_NODES) ? counts[gid] : 0;
#pragma unroll
    for (int off = 32; off; off >>= 1) s += __shfl_down(s, off);
    if ((tid & 63) == 0) lsum[tid >> 6] = s;
    __syncthreads();
    if (tid == 0) block_sums[blockIdx.x] = lsum[0] + lsum[1] + lsum[2] + lsum[3];
}

// ---------------- scan phase 2 (merged) ----------------
__global__ __launch_bounds__(256) void scan_final(const int* __restrict__ counts,
                                                  const int* __restrict__ block_sums,
                                                  int* __restrict__ row_start) {
    __shared__ int sh[256];
    __shared__ int bs[256];
    int tid = threadIdx.x;
    int gid = blockIdx.x * 256 + tid;
    sh[tid] = (gid < N_NODES) ? counts[gid] : 0;
    bs[tid] = (tid < SCAN_NB) ? block_sums[tid] : 0;
    __syncthreads();
    for (int off = 1; off < 256; off <<= 1) {
        int t1 = (tid >= off) ? sh[tid - off] : 0;
        int t2 = (tid >= off) ? bs[tid - off] : 0;
        __syncthreads();
        sh[tid] += t1;
        bs[tid] += t2;
        __syncthreads();
    }
    int boff = (blockIdx.x == 0) ? 0 : bs[blockIdx.x - 1];
    int excl = (tid == 0) ? 0 : sh[tid - 1];
    if (gid < N_NODES) row_start[gid] = boff + excl;
    if (gid == 0) row_start[N_NODES] = E_EDGES;
}

// ---------------- CSR fill — no atomics ----------------
__global__ void fill_kernel(const int* __restrict__ src, const int* __restrict__ dst,
                            const float* __restrict__ w, const int* __restrict__ pos,
                            const int* __restrict__ row_start,
                            int2* __restrict__ csr_ew) {
    int e = blockIdx.x * blockDim.x + threadIdx.x;
    if (e >= E_EDGES) return;
    int d = dst[e];
    int idx = row_start[d] + pos[e];
    int2 rec;
    rec.x = src[e];
    rec.y = __float_as_int(w[e]);
    csr_ew[idx] = rec;
}

// ---------------- gather: 16 lanes/node, 2-edge unroll ----------------
__global__ __launch_bounds__(256) void gather_kernel(const u16* __restrict__ vbf,
                                                     const int* __restrict__ row_start,
                                                     const int2* __restrict__ csr_ew,
                                                     const float* __restrict__ eps_p,
                                                     u16* __restrict__ vagg) {
    int node = blockIdx.x * 16 + (threadIdx.x >> 4);
    if (node >= N_NODES) return;
    int c8 = (threadIdx.x & 15) << 3;
    int beg = row_start[node];
    int end = row_start[node + 1];
    float a[8] = {};
    int j = beg;
    for (; j + 1 < end; j += 2) {
        int2 e0 = csr_ew[j];
        int2 e1 = csr_ew[j + 1];
        float w0 = __int_as_float(e0.y);
        float w1 = __int_as_float(e1.y);
        float4 r0 = *(const float4*)(vbf + (size_t)e0.x * D_INF + c8);
        float4 r1 = *(const float4*)(vbf + (size_t)e1.x * D_INF + c8);
        const u16* p0 = (const u16*)&r0;
        const u16* p1 = (const u16*)&r1;
#pragma unroll
        for (int t = 0; t < 8; ++t) a[t] += w0 * bf2f(p0[t]);
#pragma unroll
        for (int t = 0; t < 8; ++t) a[t] += w1 * bf2f(p1[t]);
    }
    if (j < end) {
        int2 e0 = csr_ew[j];
        float w0 = __int_as_float(e0.y);
        float4 r0 = *(const float4*)(vbf + (size_t)e0.x * D_INF + c8);
        const u16* p0 = (const u16*)&r0;
#pragma unroll
        for (int t = 0; t < 8; ++t) a[t] += w0 * bf2f(p0[t]);
    }
    float e = eps_p[0];
    float4 rn = *(const float4*)(vbf + (size_t)node * D_INF + c8);
    const u16* pn = (const u16*)&rn;
    u16 o[8];
#pragma unroll
    for (int t = 0; t < 8; ++t) o[t] = f2bf(a[t] + e * bf2f(pn[t]));
    *(float4*)(vagg + (size_t)node * D_INF + c8) = *(const float4*)o;
}

// ---------------- MFMA GEMM + bias + per-block BN partials ----------------
// Full-K LDS staging of A (in CHUNKS chunks), B fragments direct from global
// (128 KB weight matrix, L2-resident). MT=64 rows/block, 8 waves (2x4),
// grid = 782 blocks (~3/CU). Zero barriers inside the MFMA stream per chunk.
// FUSE: A' = relu(A + a_shift[k]) applied during LDS staging (BN1 scale is
// pre-folded into Bt rows).
// LDS stride = KC+8 u16: row stride 272/528 B == 4 banks mod 32 -> lanes 0-7
// cover all 32 banks, 2-way aliasing = free (m136).
template<int MT, int NT, int TH, int KC, int KTOT, int FUSE>
__global__ __launch_bounds__(TH) void mfma_gemm_bn(
        const u16* __restrict__ A, const u16* __restrict__ Bt,
        const float* __restrict__ bias,
        const float* __restrict__ a_shift,
        u16* __restrict__ Cout,
        float* __restrict__ psum, float* __restrict__ psq,
        int M) {
    constexpr int WCW = 4;               // col wave-groups
    constexpr int WRW = TH / 64 / WCW;   // row wave-groups (2)
    constexpr int WMS = MT / WRW;        // rows per wave (32)
    constexpr int WNS = NT / WCW;        // cols per wave
    constexpr int MI = WMS / 16;         // 2
    constexpr int NJ = WNS / 16;         // 8 (GEMM1) / 2 (GEMM2)
    constexpr int STRIDE = KC + 8;       // u16
    constexpr int KSC = KC / 32;         // ksteps per chunk
    constexpr int CHUNKS = KTOT / KC;
    constexpr int UPR = KC / 8;          // float4 units per row
    constexpr int UNITS = MT * UPR;
    constexpr int NU = UNITS / TH;
    static_assert(NU * TH == UNITS, "staging units must divide thread count");
    constexpr int SA = MT * STRIDE * 2;
    constexpr int SO = MT * 68 * 4;
    constexpr int SR = NT * 8;
    constexpr int SMEM_BYTES = SA > SO ? (SA > SR ? SA : SR) : (SO > SR ? SO : SR);
    __shared__ __align__(16) char smem_raw[SMEM_BYTES];
    u16* As = (u16*)smem_raw;

    const int bm = blockIdx.x * MT;
    const int tid = threadIdx.x;
    const int wave = tid >> 6, lane = tid & 63;
    const int wr = wave >> 2, wc = wave & 3;
    const int wm = wr * WMS;
    const int wn = wc * WNS;
    const int lm = lane & 15, quad = lane >> 4;

    floatx4 acc[MI][NJ] = {};
    float4 areg[NU];

    // ---- chunk staging helpers ----
    auto load_chunk = [&](int chunk) {
#pragma unroll
        for (int u = 0; u < NU; ++u) {
            int c = tid + u * TH;
            int r = c / UPR;
            int kk = (c % UPR) * 8;
            float4 av = make_float4(0.f, 0.f, 0.f, 0.f);
            int row = bm + r;
            if (row < M) av = *(const float4*)(A + (size_t)row * KTOT + chunk * KC + kk);
            areg[u] = av;
        }
    };
    auto write_chunk = [&](int chunk) {
#pragma unroll
        for (int u = 0; u < NU; ++u) {
            int c = tid + u * TH;
            int r = c / UPR;
            int kk = (c % UPR) * 8;
            float4 av = areg[u];
            if constexpr (FUSE) {
                if (bm + r < M) {
                    u16* ab = (u16*)&av;
                    int ka = chunk * KC + kk;
                    const float4 h0 = *(const float4*)(a_shift + ka);
                    const float4 h1 = *(const float4*)(a_shift + ka + 4);
                    ab[0] = f2bf(fmaxf(0.f, bf2f(ab[0]) + h0.x));
                    ab[1] = f2bf(fmaxf(0.f, bf2f(ab[1]) + h0.y));
                    ab[2] = f2bf(fmaxf(0.f, bf2f(ab[2]) + h0.z));
                    ab[3] = f2bf(fmaxf(0.f, bf2f(ab[3]) + h0.w));
                    ab[4] = f2bf(fmaxf(0.f, bf2f(ab[4]) + h1.x));
                    ab[5] = f2bf(fmaxf(0.f, bf2f(ab[5]) + h1.y));
                    ab[6] = f2bf(fmaxf(0.f, bf2f(ab[6]) + h1.z));
                    ab[7] = f2bf(fmaxf(0.f, bf2f(ab[7]) + h1.w));
                }
            }
            *(float4*)&As[r * STRIDE + kk] = av;
        }
    };
    auto compute_chunk = [&](int chunk) {
#pragma unroll
        for (int ks = 0; ks < KSC; ++ks) {
            short8 af[MI], bf[NJ];
#pragma unroll
            for (int i = 0; i < MI; ++i)
                af[i] = *(const short8*)&As[(wm + i * 16 + lm) * STRIDE + ks * 32 + quad * 8];
#pragma unroll
            for (int j = 0; j < NJ; ++j)
                bf[j] = *(const short8*)(Bt + (size_t)(wn + j * 16 + lm) * KTOT
                                         + chunk * KC + ks * 32 + quad * 8);
#pragma unroll
            for (int i = 0; i < MI; ++i)
#pragma unroll
                for (int j = 0; j < NJ; ++j)
                    acc[i][j] = __builtin_amdgcn_mfma_f32_16x16x32_bf16(af[i], bf[j], acc[i][j], 0, 0, 0);
        }
    };

    // ---- main: stage + compute, minimal barriers ----
    load_chunk(0);
    write_chunk(0);
    if (CHUNKS > 1) load_chunk(1);      // issue next chunk's HBM loads early (T14)
    __syncthreads();
    compute_chunk(0);
#pragma unroll
    for (int ch = 1; ch < CHUNKS; ++ch) {
        __syncthreads();                // all waves done reading As
        write_chunk(ch);                // waits on the early-issued loads
        if (ch + 1 < CHUNKS) load_chunk(ch + 1);
        __syncthreads();
        compute_chunk(ch);
    }

    // ---- per-block BN partials ----
    __syncthreads();
    float* redS = (float*)smem_raw;
    float* redQ = redS + NT;
    for (int c = tid; c < NT; c += TH) { redS[c] = 0.f; redQ[c] = 0.f; }
    __syncthreads();
    float bjv[NJ];
#pragma unroll
    for (int j = 0; j < NJ; ++j) {
        int cl = wn + j * 16 + lm;
        bjv[j] = bias[cl];
        float s = 0.f, q = 0.f;
#pragma unroll
        for (int i = 0; i < MI; ++i) {
            int row0 = bm + wm + i * 16 + quad * 4;
#pragma unroll
            for (int r = 0; r < 4; ++r) {
                if (row0 + r < M) {
                    float x = acc[i][j][r] + bjv[j];
                    s += x; q += x * x;
                }
            }
        }
        s += __shfl_xor(s, 16); q += __shfl_xor(q, 16);
        s += __shfl_xor(s, 32); q += __shfl_xor(q, 32);
        if (quad == 0) {
            atomicAdd(&redS[cl], s);
            atomicAdd(&redQ[cl], q);
        }
    }
    __syncthreads();
    for (int c = tid; c < NT; c += TH) {
        psum[(size_t)blockIdx.x * NT + c] = redS[c];
        psq [(size_t)blockIdx.x * NT + c] = redQ[c];
    }

    // ---- coalesced bf16 output via LDS obuf: MT rows x 64-col passes ----
    float* obuf = (float*)smem_raw;
#pragma unroll
    for (int jh = 0; jh < NT / 64; ++jh) {
        __syncthreads();
#pragma unroll
        for (int j = 0; j < NJ; ++j) {
            int gc = wn + j * 16;
            if (gc >= jh * 64 && gc < jh * 64 + 64) {
                int cp = gc - jh * 64 + lm;
#pragma unroll
                for (int i = 0; i < MI; ++i)
#pragma unroll
                    for (int r = 0; r < 4; ++r)
                        obuf[(wm + i * 16 + quad * 4 + r) * 68 + cp] =
                            acc[i][j][r] + bjv[j];
            }
        }
        __syncthreads();
        int lr = tid >> 2;
        int seg = (tid & 3) << 4;
        if (lr < MT) {
            int grow = bm + lr;
            if (grow < M) {
                u16 ob[16];
#pragma unroll
                for (int t = 0; t < 4; ++t) {
                    float4 f = *(float4*)&obuf[lr * 68 + seg + t * 4];
                    ob[t * 4 + 0] = f2bf(f.x);
                    ob[t * 4 + 1] = f2bf(f.y);
                    ob[t * 4 + 2] = f2bf(f.z);
                    ob[t * 4 + 3] = f2bf(f.w);
                }
                u16* dstp = Cout + (size_t)grow * NT + jh * 64 + seg;
                *(float4*)dstp       = *(float4*)(ob);
                *(float4*)(dstp + 8) = *(float4*)(ob + 8);
            }
        }
    }
}

// ---------------- BN finalize (parallel reduce of per-block partials) ----------------
// tshift (optional): shift/scale for downstream scale-folded ReLU fusion
__global__ __launch_bounds__(1024) void bn_finalize_kernel(
        const float* __restrict__ psum, const float* __restrict__ psq,
        const float* __restrict__ gamma, const float* __restrict__ beta,
        float* __restrict__ scale, float* __restrict__ shift, float* __restrict__ tshift,
        int nblocks, int Ncols, float inv_n) {
    __shared__ float shS[16][64];
    __shared__ float shQ[16][64];
    const int tx = threadIdx.x;
    const int ty = threadIdx.y;
    const int c = blockIdx.x * 64 + tx;
    float s = 0.f, q = 0.f;
    for (int b = ty; b < nblocks; b += 16) {
        s += psum[(size_t)b * Ncols + c];
        q += psq [(size_t)b * Ncols + c];
    }
    shS[ty][tx] = s;
    shQ[ty][tx] = q;
    __syncthreads();
    if (ty == 0) {
        float S = 0.f, Q = 0.f;
#pragma unroll
        for (int r = 0; r < 16; ++r) { S += shS[r][tx]; Q += shQ[r][tx]; }
        float m = S * inv_n;
        float var = Q * inv_n - m * m;
        float rs = rsqrtf(var + 1e-5f);
        float sc = gamma[c] * rs;
        float sh = beta[c] - sc * m;
        scale[c] = sc;
        shift[c] = sh;
        if (tshift) tshift[c] = sh / sc;
    }
}

// ---------------- BN2 apply + ReLU: x2 bf16 -> d_out fp32 ----------------
__global__ void bn2_apply_kernel(const u16* __restrict__ X, float* __restrict__ Y,
                                 const float* __restrict__ scale,
                                 const float* __restrict__ shift, int n8) {
    int i = blockIdx.x * blockDim.x + threadIdx.x;
    if (i >= n8) return;
    int c = (i & 15) << 3;
    float4 raw = ((const float4*)X)[i];
    const u16* xb = (const u16*)&raw;
    float4 sc0 = *(const float4*)(scale + c);
    float4 sc1 = *(const float4*)(scale + c + 4);
    float4 sh0 = *(const float4*)(shift + c);
    float4 sh1 = *(const float4*)(shift + c + 4);
    float4 y0, y1;
    y0.x = fmaxf(0.f, bf2f(xb[0]) * sc0.x + sh0.x);
    y0.y = fmaxf(0.f, bf2f(xb[1]) * sc0.y + sh0.y);
    y0.z = fmaxf(0.f, bf2f(xb[2]) * sc0.z + sh0.z);
    y0.w = fmaxf(0.f, bf2f(xb[3]) * sc0.w + sh0.w);
    y1.x = fmaxf(0.f, bf2f(xb[4]) * sc1.x + sh1.x);
    y1.y = fmaxf(0.f, bf2f(xb[5]) * sc1.y + sh1.y);
    y1.z = fmaxf(0.f, bf2f(xb[6]) * sc1.z + sh1.z);
    y1.w = fmaxf(0.f, bf2f(xb[7]) * sc1.w + sh1.w);
    ((float4*)Y)[i * 2]     = y0;
    ((float4*)Y)[i * 2 + 1] = y1;
}

extern "C" void kernel_launch(void* const* d_in, const int* in_sizes, int n_in,
                              void* d_out, int out_size, void* d_ws, size_t ws_size,
                              hipStream_t stream) {
    const float* v    = (const float*)d_in[0];
    const int* src    = (const int*)d_in[1];
    const int* dst    = (const int*)d_in[2];
    const float* ew   = (const float*)d_in[3];
    const float* eps  = (const float*)d_in[4];
    const float* W1   = (const float*)d_in[5];
    const float* b1   = (const float*)d_in[6];
    const float* g1   = (const float*)d_in[7];
    const float* be1  = (const float*)d_in[8];
    const float* W2   = (const float*)d_in[9];
    const float* b2   = (const float*)d_in[10];
    const float* g2   = (const float*)d_in[11];
    const float* be2  = (const float*)d_in[12];
    float* out = (float*)d_out;

    // ---- workspace layout (bytes) ----
    char* base = (char*)d_ws;
    u16* x1   = (u16*)(base);                      // [N,512] bf16
    u16* vbf  = (u16*)(base + 51200000ull);        // [N,128] bf16
    u16* vagg = (u16*)(base + 64000000ull);        // [N,128] bf16
    u16* x2   = (u16*)(base + 76800000ull);        // [N,128] bf16 raw pre-BN2
    u16* W1t  = (u16*)(base + 89600000ull);        // 512x128 bf16
    u16* W2t  = (u16*)(base + 89731072ull);        // 128x512 bf16 (BN1-scale folded)
    float* psum2  = (float*)(base + 89862144ull);  // [782][128] fp32 (GEMM2)
    float* psq2   = (float*)(base + 90663168ull);  // [782][128] fp32
    float* scale1 = (float*)(base + 91464192ull);  // 512
    float* shift1 = scale1 + 512;
    float* scale2 = shift1 + 512;
    float* shift2 = scale2 + 128;
    float* tshift1 = shift2 + 128;                 // 512 (shift1/scale1)
    int* counts     = (int*)(tshift1 + 512);       // 50,000
    int* row_start  = counts + 50000;              // 50,001 (+pad 3)
    int* pos        = row_start + 50004;           // 800,000
    int2* csr_ew    = (int2*)(pos + 800000);       // 800,000 * 8 B
    int* block_sums = (int*)(csr_ew + 800000);     // 256
    // GEMM1 BN partials [782][512] f32 (1.6 MB each) overlay the CSR scratch,
    // which is dead once gather_kernel has consumed csr_ew/pos.
    float* psum1 = (float*)pos;                    // 1,601,536 B <= 3,200,000 B
    float* psq1  = (float*)csr_ew;                 // 1,601,536 B <= 6,400,000 B

    hipMemsetAsync(counts, 0, (size_t)50000 * sizeof(int), stream);

    // CSR build + casts
    cast_v_kernel<<<(N_NODES * D_INF / 8 + 255) / 256, 256, 0, stream>>>(v, vbf);
    hist_kernel<<<(EQ + 255) / 256, 256, 0, stream>>>(dst, counts, pos);
    prep_w1_kernel<<<(128 * 512 + 255) / 256, 256, 0, stream>>>(W1, W1t);
    reduce_kernel<<<SCAN_NB, 256, 0, stream>>>(counts, block_sums);
    scan_final<<<SCAN_NB, 256, 0, stream>>>(counts, block_sums, row_start);
    fill_kernel<<<(E_EDGES + 255) / 256, 256, 0, stream>>>(src, dst, ew, pos, row_start, csr_ew);
    gather_kernel<<<(N_NODES + 15) / 16, 256, 0, stream>>>(vbf, row_start, csr_ew, eps, vagg);

    // GEMM1: x1 = vagg @ W1 + b1 (bf16 raw) + BN1 partials
    // 64x512 tile, 8 waves, K=128 staged once, B direct from L2, 782 blocks
    mfma_gemm_bn<64, 512, 512, 128, 128, 0><<<G2BLKS, 512, 0, stream>>>(
        vagg, W1t, b1, nullptr, x1, psum1, psq1, N_NODES);
    bn_finalize_kernel<<<D_HIDF / 64, dim3(64, 16), 0, stream>>>(
        psum1, psq1, g1, be1, scale1, shift1, tshift1, G2BLKS, D_HIDF, 1.0f / N_NODES);

    // fold BN1 scale into W2 rows (scale1 > 0 since gamma1 = 1)
    prep_w2_kernel<<<(512 * 128 + 255) / 256, 256, 0, stream>>>(W2, scale1, W2t);

    // GEMM2: x2 = relu(x1 + tshift1) @ (scale1*W2) + b2 + BN2 partials
    // 64x128 tile, 8 waves, K=512 staged in 2 chunks (loads issued early), B direct
    mfma_gemm_bn<64, 128, 512, 256, 512, 1><<<G2BLKS, 512, 0, stream>>>(
        x1, W2t, b2, tshift1, x2, psum2, psq2, N_NODES);
    bn_finalize_kernel<<<D_OUTF / 64, dim3(64, 16), 0, stream>>>(
        psum2, psq2, g2, be2, scale2, shift2, nullptr, G2BLKS, D_OUTF, 1.0f / N_NODES);

    // BN2 apply + ReLU: x2 (bf16) -> d_out (fp32)
    {
        int n8 = N_NODES * D_OUTF / 8;
        bn2_apply_kernel<<<(n8 + 255) / 256, 256, 0, stream>>>(x2, out, scale2, shift2, n8);
    }
}

// Round 3
// 281.188 us; speedup vs baseline: 1.2552x; 1.2552x over previous
//
#include <hip/hip_runtime.h>

#define N_NODES 50000
#define E_EDGES 800000
#define D_INF   128
#define D_HIDF  512
#define D_OUTF  128
#define SCAN_NB ((N_NODES + 255) / 256)   // 196 blocks
#define M1BLKS  ((N_NODES + 255) / 256)   // 196 row-blocks GEMM1 (256-row tiles)
#define M2BLKS  ((N_NODES + 127) / 128)   // 391 row-blocks GEMM2 (128-row tiles)
#define EQ      (E_EDGES / 4)             // 200,000 edges per ILP slot

typedef unsigned short u16;
typedef __attribute__((ext_vector_type(8))) short short8;
typedef __attribute__((ext_vector_type(4))) float floatx4;
typedef const __attribute__((address_space(1))) void gas_t;
typedef __attribute__((address_space(3))) void las_t;

__device__ __forceinline__ u16 f2bf(float f) {
    union { float f; unsigned u; } v; v.f = f;
    unsigned r = (v.u + 0x7fffu + ((v.u >> 16) & 1u)) >> 16;
    return (u16)r;
}
__device__ __forceinline__ float bf2f(u16 b) {
    union { unsigned u; float f; } v; v.u = ((unsigned)b) << 16; return v.f;
}

// ---------------- cast v -> bf16 ----------------
__global__ void cast_v_kernel(const float* __restrict__ v, u16* __restrict__ vbf) {
    int i = blockIdx.x * blockDim.x + threadIdx.x;
    if (i >= N_NODES * D_INF / 8) return;
    const float4 a = ((const float4*)v)[i * 2];
    const float4 b = ((const float4*)v)[i * 2 + 1];
    u16 o[8];
    o[0] = f2bf(a.x); o[1] = f2bf(a.y); o[2] = f2bf(a.z); o[3] = f2bf(a.w);
    o[4] = f2bf(b.x); o[5] = f2bf(b.y); o[6] = f2bf(b.z); o[7] = f2bf(b.w);
    ((float4*)vbf)[i] = *(const float4*)o;
}

// ---------------- hist + per-edge pos ----------------
__global__ void hist_kernel(const int* __restrict__ dst, int* __restrict__ counts,
                            int* __restrict__ pos) {
    int t = blockIdx.x * blockDim.x + threadIdx.x;
    if (t >= EQ) return;
    int d0 = dst[t];
    int d1 = dst[t + EQ];
    int d2 = dst[t + 2 * EQ];
    int d3 = dst[t + 3 * EQ];
    int p0 = atomicAdd(&counts[d0], 1);
    int p1 = atomicAdd(&counts[d1], 1);
    int p2 = atomicAdd(&counts[d2], 1);
    int p3 = atomicAdd(&counts[d3], 1);
    pos[t]          = p0;
    pos[t + EQ]     = p1;
    pos[t + 2 * EQ] = p2;
    pos[t + 3 * EQ] = p3;
}

// ---------------- weight prep: W1 transpose early ----------------
__global__ void prep_w1_kernel(const float* __restrict__ W1, u16* __restrict__ W1t) {
    int idx = blockIdx.x * blockDim.x + threadIdx.x;
    if (idx >= 128 * 512) return;
    int k1 = idx >> 9, n1 = idx & 511;      // W1 [128][512]
    W1t[n1 * 128 + k1] = f2bf(W1[idx]);
}

// ---- W2 transpose with BN1 scale folded into its rows (after bn_finalize1) ----
__global__ void prep_w2_kernel(const float* __restrict__ W2, const float* __restrict__ scale1,
                               u16* __restrict__ W2t) {
    int idx = blockIdx.x * blockDim.x + threadIdx.x;
    if (idx >= 512 * 128) return;
    int k2 = idx >> 7, n2 = idx & 127;      // W2 [512][128]
    W2t[n2 * 512 + k2] = f2bf(W2[idx] * scale1[k2]);
}

// ---------------- scan phase 1: per-block sums ----------------
__global__ __launch_bounds__(256) void reduce_kernel(const int* __restrict__ counts,
                                                     int* __restrict__ block_sums) {
    __shared__ int lsum[4];
    int tid = threadIdx.x;
    int gid = blockIdx.x * 256 + tid;
    int s = (gid < N_NODES) ? counts[gid] : 0;
#pragma unroll
    for (int off = 32; off; off >>= 1) s += __shfl_down(s, off);
    if ((tid & 63) == 0) lsum[tid >> 6] = s;
    __syncthreads();
    if (tid == 0) block_sums[blockIdx.x] = lsum[0] + lsum[1] + lsum[2] + lsum[3];
}

// ---------------- scan phase 2 (merged) ----------------
__global__ __launch_bounds__(256) void scan_final(const int* __restrict__ counts,
                                                  const int* __restrict__ block_sums,
                                                  int* __restrict__ row_start) {
    __shared__ int sh[256];
    __shared__ int bs[256];
    int tid = threadIdx.x;
    int gid = blockIdx.x * 256 + tid;
    sh[tid] = (gid < N_NODES) ? counts[gid] : 0;
    bs[tid] = (tid < SCAN_NB) ? block_sums[tid] : 0;
    __syncthreads();
    for (int off = 1; off < 256; off <<= 1) {
        int t1 = (tid >= off) ? sh[tid - off] : 0;
        int t2 = (tid >= off) ? bs[tid - off] : 0;
        __syncthreads();
        sh[tid] += t1;
        bs[tid] += t2;
        __syncthreads();
    }
    int boff = (blockIdx.x == 0) ? 0 : bs[blockIdx.x - 1];
    int excl = (tid == 0) ? 0 : sh[tid - 1];
    if (gid < N_NODES) row_start[gid] = boff + excl;
    if (gid == 0) row_start[N_NODES] = E_EDGES;
}

// ---------------- CSR fill — no atomics ----------------
__global__ void fill_kernel(const int* __restrict__ src, const int* __restrict__ dst,
                            const float* __restrict__ w, const int* __restrict__ pos,
                            const int* __restrict__ row_start,
                            int2* __restrict__ csr_ew) {
    int e = blockIdx.x * blockDim.x + threadIdx.x;
    if (e >= E_EDGES) return;
    int d = dst[e];
    int idx = row_start[d] + pos[e];
    int2 rec;
    rec.x = src[e];
    rec.y = __float_as_int(w[e]);
    csr_ew[idx] = rec;
}

// ---------------- gather: 16 lanes/node, 2-edge unroll ----------------
__global__ __launch_bounds__(256) void gather_kernel(const u16* __restrict__ vbf,
                                                     const int* __restrict__ row_start,
                                                     const int2* __restrict__ csr_ew,
                                                     const float* __restrict__ eps_p,
                                                     u16* __restrict__ vagg) {
    int node = blockIdx.x * 16 + (threadIdx.x >> 4);
    if (node >= N_NODES) return;
    int c8 = (threadIdx.x & 15) << 3;
    int beg = row_start[node];
    int end = row_start[node + 1];
    float a[8] = {};
    int j = beg;
    for (; j + 1 < end; j += 2) {
        int2 e0 = csr_ew[j];
        int2 e1 = csr_ew[j + 1];
        float w0 = __int_as_float(e0.y);
        float w1 = __int_as_float(e1.y);
        float4 r0 = *(const float4*)(vbf + (size_t)e0.x * D_INF + c8);
        float4 r1 = *(const float4*)(vbf + (size_t)e1.x * D_INF + c8);
        const u16* p0 = (const u16*)&r0;
        const u16* p1 = (const u16*)&r1;
#pragma unroll
        for (int t = 0; t < 8; ++t) a[t] += w0 * bf2f(p0[t]);
#pragma unroll
        for (int t = 0; t < 8; ++t) a[t] += w1 * bf2f(p1[t]);
    }
    if (j < end) {
        int2 e0 = csr_ew[j];
        float w0 = __int_as_float(e0.y);
        float4 r0 = *(const float4*)(vbf + (size_t)e0.x * D_INF + c8);
        const u16* p0 = (const u16*)&r0;
#pragma unroll
        for (int t = 0; t < 8; ++t) a[t] += w0 * bf2f(p0[t]);
    }
    float e = eps_p[0];
    float4 rn = *(const float4*)(vbf + (size_t)node * D_INF + c8);
    const u16* pn = (const u16*)&rn;
    u16 o[8];
#pragma unroll
    for (int t = 0; t < 8; ++t) o[t] = f2bf(a[t] + e * bf2f(pn[t]));
    *(float4*)(vagg + (size_t)node * D_INF + c8) = *(const float4*)o;
}

// ---------------- MFMA GEMM + bias + per-block BN partials ----------------
// Round-0 skeleton (2 barriers/kstep, BK=32) with global_load_lds(16B) staging.
// AGL=1: A staged via global_load_lds into linear [MT][32] u16 LDS with the
//        both-sides slot swizzle (inverse-swizzled global source lane map +
//        same XOR on the ds_read side; LDS dest stays linear — rule #21).
// AGL=0: A reg-staged at stride 48 (FUSE transform needs registers).
// B always staged via global_load_lds (linear [NT][32] + swizzle).
// FUSE: A' = relu(A + a_shift[k]); BN1 scale pre-folded into Bt rows.
// Wave layout: 8 waves = 4 row-groups x 2 col-groups; WNS must be 64.
template<int MT, int NT, int FUSE, int AGL, int KTOT>
__global__ __launch_bounds__(512) void mfma_gemm_bn(
        const u16* __restrict__ A, const u16* __restrict__ Bt,
        const float* __restrict__ bias,
        const float* __restrict__ a_shift,
        u16* __restrict__ Cout,
        float* __restrict__ psum, float* __restrict__ psq,
        int M, int Ncols) {
    constexpr int WMS = MT / 4;
    constexpr int WNS = NT / 2;
    static_assert(WNS == 64, "col wave span must be 64");
    constexpr int MI = WMS / 16;
    constexpr int NJ = WNS / 16;
    constexpr int ASTR = AGL ? 32 : 48;       // u16 per row
    constexpr int ABYTES = MT * ASTR * 2;
    constexpr int STG = ABYTES + NT * 64;
    constexpr int RP = 128;                   // rows per output pass
    constexpr int RH = MT / RP;
    constexpr int JH = NT / 64;
    constexpr int OB = RP * 68 * 4;
    constexpr int SMEM = STG > OB ? STG : OB;
    __shared__ __align__(16) char smem[SMEM];
    u16* As = (u16*)smem;
    u16* Bs = (u16*)(smem + ABYTES);

    // staging decomposition: 1 KB chunks (16 rows x 64 B), one wave-issue each
    constexpr int ACH = AGL ? MT / 16 : 0;
    constexpr int BCH = NT / 16;
    constexpr int CPW = (ACH + BCH) / 8;
    static_assert(CPW * 8 == ACH + BCH, "chunks must divide waves");
    constexpr int AU = AGL ? 0 : (MT * 4) / 512;   // reg-staged 16B units
    static_assert(AGL || AU * 512 == MT * 4, "A units must divide threads");

    const int bm = blockIdx.y * MT;
    const int bn = blockIdx.x * NT;
    const int tid = threadIdx.x;
    const int wave = tid >> 6, lane = tid & 63;
    const int wr = wave >> 1, wc = wave & 1;
    const int wm = wr * WMS;
    const int wn = wc * WNS;
    const int lm = lane & 15, quad = lane >> 4;

    floatx4 acc[MI][NJ] = {};

    const int ksteps = KTOT >> 5;
    for (int ks = 0; ks < ksteps; ++ks) {
        const int k0 = ks << 5;
        // ---- stage: global_load_lds chunks (wave-uniform chunk ids) ----
        {
            const int sub = lane >> 2, s = lane & 3;
#pragma unroll
            for (int t = 0; t < CPW; ++t) {
                int ch = wave * CPW + t;
                if (AGL && ch < ACH) {
                    int row = ch * 16 + sub;
                    int grow = bm + row; if (grow > M - 1) grow = M - 1;  // clamp; rows>=M discarded later
                    int ss = s ^ (row & 3);
                    __builtin_amdgcn_global_load_lds(
                        (gas_t*)(A + (size_t)grow * KTOT + k0 + ss * 8),
                        (las_t*)(As + row * 32 + s * 8), 16, 0, 0);
                } else {
                    int row = (ch - ACH) * 16 + sub;
                    int ss = s ^ (row & 3);
                    __builtin_amdgcn_global_load_lds(
                        (gas_t*)(Bt + (size_t)(bn + row) * KTOT + k0 + ss * 8),
                        (las_t*)(Bs + row * 32 + s * 8), 16, 0, 0);
                }
            }
        }
        // ---- reg-staged A (FUSE path) ----
        if constexpr (!AGL) {
#pragma unroll
            for (int u = 0; u < AU; ++u) {
                int c = tid + u * 512;
                int r = c >> 2, s = c & 3;
                float4 av = make_float4(0.f, 0.f, 0.f, 0.f);
                int grow = bm + r;
                if (grow < M) {
                    av = *(const float4*)(A + (size_t)grow * KTOT + k0 + s * 8);
                    if constexpr (FUSE) {
                        u16* ab = (u16*)&av;
                        const float4 h0 = *(const float4*)(a_shift + k0 + s * 8);
                        const float4 h1 = *(const float4*)(a_shift + k0 + s * 8 + 4);
                        ab[0] = f2bf(fmaxf(0.f, bf2f(ab[0]) + h0.x));
                        ab[1] = f2bf(fmaxf(0.f, bf2f(ab[1]) + h0.y));
                        ab[2] = f2bf(fmaxf(0.f, bf2f(ab[2]) + h0.z));
                        ab[3] = f2bf(fmaxf(0.f, bf2f(ab[3]) + h0.w));
                        ab[4] = f2bf(fmaxf(0.f, bf2f(ab[4]) + h1.x));
                        ab[5] = f2bf(fmaxf(0.f, bf2f(ab[5]) + h1.y));
                        ab[6] = f2bf(fmaxf(0.f, bf2f(ab[6]) + h1.z));
                        ab[7] = f2bf(fmaxf(0.f, bf2f(ab[7]) + h1.w));
                    }
                }
                *(float4*)&As[r * 48 + s * 8] = av;
            }
        }
        __syncthreads();   // drains vmcnt (gload_lds) + lgkm before use
        short8 af[MI], bfr[NJ];
#pragma unroll
        for (int i = 0; i < MI; ++i) {
            int row = wm + i * 16 + lm;
            if constexpr (AGL)
                af[i] = *(const short8*)&As[row * 32 + (quad ^ (row & 3)) * 8];
            else
                af[i] = *(const short8*)&As[row * 48 + quad * 8];
        }
#pragma unroll
        for (int j = 0; j < NJ; ++j) {
            int row = wn + j * 16 + lm;
            bfr[j] = *(const short8*)&Bs[row * 32 + (quad ^ (row & 3)) * 8];
        }
#pragma unroll
        for (int i = 0; i < MI; ++i)
#pragma unroll
            for (int j = 0; j < NJ; ++j)
                acc[i][j] = __builtin_amdgcn_mfma_f32_16x16x32_bf16(af[i], bfr[j], acc[i][j], 0, 0, 0);
        __syncthreads();
    }

    // ---- per-block BN partials ----
    float* redS = (float*)smem;
    float* redQ = redS + NT;
    if (tid < NT) { redS[tid] = 0.f; redQ[tid] = 0.f; }
    __syncthreads();
    float bjv[NJ];
#pragma unroll
    for (int j = 0; j < NJ; ++j) {
        int cl = wn + j * 16 + lm;
        bjv[j] = bias[bn + cl];
        float s = 0.f, q = 0.f;
#pragma unroll
        for (int i = 0; i < MI; ++i) {
            int row0 = bm + wm + i * 16 + quad * 4;
#pragma unroll
            for (int r = 0; r < 4; ++r) {
                if (row0 + r < M) {
                    float x = acc[i][j][r] + bjv[j];
                    s += x; q += x * x;
                }
            }
        }
        s += __shfl_xor(s, 16); q += __shfl_xor(q, 16);
        s += __shfl_xor(s, 32); q += __shfl_xor(q, 32);
        if (quad == 0) {
            atomicAdd(&redS[cl], s);
            atomicAdd(&redQ[cl], q);
        }
    }
    __syncthreads();
    if (tid < NT) {
        psum[(size_t)blockIdx.y * Ncols + bn + tid] = redS[tid];
        psq [(size_t)blockIdx.y * Ncols + bn + tid] = redQ[tid];
    }

    // ---- coalesced bf16 output via LDS obuf: RP rows x 64-col passes ----
    float* obuf = (float*)smem;
#pragma unroll
    for (int rh = 0; rh < RH; ++rh) {
#pragma unroll
        for (int jh = 0; jh < JH; ++jh) {
            __syncthreads();
            if ((wm / RP) == rh && (wn >> 6) == jh) {
                int rbase = wm % RP;
#pragma unroll
                for (int i = 0; i < MI; ++i)
#pragma unroll
                    for (int j = 0; j < NJ; ++j) {
                        int cp = j * 16 + lm;
#pragma unroll
                        for (int r = 0; r < 4; ++r)
                            obuf[(rbase + i * 16 + quad * 4 + r) * 68 + cp] =
                                acc[i][j][r] + bjv[j];
                    }
            }
            __syncthreads();
            int lr = tid >> 2;
            int seg = (tid & 3) << 4;
            int grow = bm + rh * RP + lr;
            if (grow < M) {
                u16 ob[16];
#pragma unroll
                for (int t = 0; t < 4; ++t) {
                    float4 f = *(float4*)&obuf[lr * 68 + seg + t * 4];
                    ob[t * 4 + 0] = f2bf(f.x);
                    ob[t * 4 + 1] = f2bf(f.y);
                    ob[t * 4 + 2] = f2bf(f.z);
                    ob[t * 4 + 3] = f2bf(f.w);
                }
                u16* dstp = Cout + (size_t)grow * Ncols + bn + jh * 64 + seg;
                *(float4*)dstp       = *(float4*)(ob);
                *(float4*)(dstp + 8) = *(float4*)(ob + 8);
            }
        }
    }
}

// ---------------- BN finalize (parallel reduce of per-block partials) ----------------
__global__ __launch_bounds__(1024) void bn_finalize_kernel(
        const float* __restrict__ psum, const float* __restrict__ psq,
        const float* __restrict__ gamma, const float* __restrict__ beta,
        float* __restrict__ scale, float* __restrict__ shift, float* __restrict__ tshift,
        int nblocks, int Ncols, float inv_n) {
    __shared__ float shS[16][64];
    __shared__ float shQ[16][64];
    const int tx = threadIdx.x;
    const int ty = threadIdx.y;
    const int c = blockIdx.x * 64 + tx;
    float s = 0.f, q = 0.f;
    for (int b = ty; b < nblocks; b += 16) {
        s += psum[(size_t)b * Ncols + c];
        q += psq [(size_t)b * Ncols + c];
    }
    shS[ty][tx] = s;
    shQ[ty][tx] = q;
    __syncthreads();
    if (ty == 0) {
        float S = 0.f, Q = 0.f;
#pragma unroll
        for (int r = 0; r < 16; ++r) { S += shS[r][tx]; Q += shQ[r][tx]; }
        float m = S * inv_n;
        float var = Q * inv_n - m * m;
        float rs = rsqrtf(var + 1e-5f);
        float sc = gamma[c] * rs;
        float sh = beta[c] - sc * m;
        scale[c] = sc;
        shift[c] = sh;
        if (tshift) tshift[c] = sh / sc;
    }
}

// ---------------- BN2 apply + ReLU: x2 bf16 -> d_out fp32 ----------------
__global__ void bn2_apply_kernel(const u16* __restrict__ X, float* __restrict__ Y,
                                 const float* __restrict__ scale,
                                 const float* __restrict__ shift, int n8) {
    int i = blockIdx.x * blockDim.x + threadIdx.x;
    if (i >= n8) return;
    int c = (i & 15) << 3;
    float4 raw = ((const float4*)X)[i];
    const u16* xb = (const u16*)&raw;
    float4 sc0 = *(const float4*)(scale + c);
    float4 sc1 = *(const float4*)(scale + c + 4);
    float4 sh0 = *(const float4*)(shift + c);
    float4 sh1 = *(const float4*)(shift + c + 4);
    float4 y0, y1;
    y0.x = fmaxf(0.f, bf2f(xb[0]) * sc0.x + sh0.x);
    y0.y = fmaxf(0.f, bf2f(xb[1]) * sc0.y + sh0.y);
    y0.z = fmaxf(0.f, bf2f(xb[2]) * sc0.z + sh0.z);
    y0.w = fmaxf(0.f, bf2f(xb[3]) * sc0.w + sh0.w);
    y1.x = fmaxf(0.f, bf2f(xb[4]) * sc1.x + sh1.x);
    y1.y = fmaxf(0.f, bf2f(xb[5]) * sc1.y + sh1.y);
    y1.z = fmaxf(0.f, bf2f(xb[6]) * sc1.z + sh1.z);
    y1.w = fmaxf(0.f, bf2f(xb[7]) * sc1.w + sh1.w);
    ((float4*)Y)[i * 2]     = y0;
    ((float4*)Y)[i * 2 + 1] = y1;
}

extern "C" void kernel_launch(void* const* d_in, const int* in_sizes, int n_in,
                              void* d_out, int out_size, void* d_ws, size_t ws_size,
                              hipStream_t stream) {
    const float* v    = (const float*)d_in[0];
    const int* src    = (const int*)d_in[1];
    const int* dst    = (const int*)d_in[2];
    const float* ew   = (const float*)d_in[3];
    const float* eps  = (const float*)d_in[4];
    const float* W1   = (const float*)d_in[5];
    const float* b1   = (const float*)d_in[6];
    const float* g1   = (const float*)d_in[7];
    const float* be1  = (const float*)d_in[8];
    const float* W2   = (const float*)d_in[9];
    const float* b2   = (const float*)d_in[10];
    const float* g2   = (const float*)d_in[11];
    const float* be2  = (const float*)d_in[12];
    float* out = (float*)d_out;

    // ---- workspace layout (bytes) ----
    char* base = (char*)d_ws;
    u16* x1   = (u16*)(base);                      // [N,512] bf16
    u16* vbf  = (u16*)(base + 51200000ull);        // [N,128] bf16
    u16* vagg = (u16*)(base + 64000000ull);        // [N,128] bf16
    u16* x2   = (u16*)(base + 76800000ull);        // [N,128] bf16 raw pre-BN2
    u16* W1t  = (u16*)(base + 89600000ull);        // 512x128 bf16
    u16* W2t  = (u16*)(base + 89731072ull);        // 128x512 bf16 (BN1-scale folded)
    float* psum   = (float*)(base + 89862144ull);  // [196][512] / [391][128] fp32
    float* psq    = (float*)(base + 90663168ull);  // same
    float* scale1 = (float*)(base + 91464192ull);  // 512
    float* shift1 = scale1 + 512;
    float* scale2 = shift1 + 512;
    float* shift2 = scale2 + 128;
    float* tshift1 = shift2 + 128;                 // 512 (shift1/scale1)
    int* counts     = (int*)(tshift1 + 512);       // 50,000
    int* row_start  = counts + 50000;              // 50,001 (+pad 3)
    int* pos        = row_start + 50004;           // 800,000
    int2* csr_ew    = (int2*)(pos + 800000);       // 800,000 * 8 B
    int* block_sums = (int*)(csr_ew + 800000);     // 256

    hipMemsetAsync(counts, 0, (size_t)50000 * sizeof(int), stream);

    // CSR build + casts
    cast_v_kernel<<<(N_NODES * D_INF / 8 + 255) / 256, 256, 0, stream>>>(v, vbf);
    hist_kernel<<<(EQ + 255) / 256, 256, 0, stream>>>(dst, counts, pos);
    prep_w1_kernel<<<(128 * 512 + 255) / 256, 256, 0, stream>>>(W1, W1t);
    reduce_kernel<<<SCAN_NB, 256, 0, stream>>>(counts, block_sums);
    scan_final<<<SCAN_NB, 256, 0, stream>>>(counts, block_sums, row_start);
    fill_kernel<<<(E_EDGES + 255) / 256, 256, 0, stream>>>(src, dst, ew, pos, row_start, csr_ew);
    gather_kernel<<<(N_NODES + 15) / 16, 256, 0, stream>>>(vbf, row_start, csr_ew, eps, vagg);

    // GEMM1: x1 = vagg @ W1 + b1 (bf16 raw) + BN1 partials
    // 256x128 tile, A+B via global_load_lds, grid (4,196)
    {
        dim3 grid(D_HIDF / 128, M1BLKS);
        mfma_gemm_bn<256, 128, 0, 1, D_INF><<<grid, 512, 0, stream>>>(
            vagg, W1t, b1, nullptr, x1, psum, psq, N_NODES, D_HIDF);
    }
    bn_finalize_kernel<<<D_HIDF / 64, dim3(64, 16), 0, stream>>>(
        psum, psq, g1, be1, scale1, shift1, tshift1, M1BLKS, D_HIDF, 1.0f / N_NODES);

    // fold BN1 scale into W2 rows (scale1 > 0 since gamma1 = 1)
    prep_w2_kernel<<<(512 * 128 + 255) / 256, 256, 0, stream>>>(W2, scale1, W2t);

    // GEMM2: x2 = relu(x1 + tshift1) @ (scale1*W2) + b2 + BN2 partials
    // 128x128 tile (A staged+transformed once), B via global_load_lds, grid (1,391)
    {
        dim3 grid(D_OUTF / 128, M2BLKS);
        mfma_gemm_bn<128, 128, 1, 0, D_HIDF><<<grid, 512, 0, stream>>>(
            x1, W2t, b2, tshift1, x2, psum, psq, N_NODES, D_OUTF);
    }
    bn_finalize_kernel<<<D_OUTF / 64, dim3(64, 16), 0, stream>>>(
        psum, psq, g2, be2, scale2, shift2, nullptr, M2BLKS, D_OUTF, 1.0f / N_NODES);

    // BN2 apply + ReLU: x2 (bf16) -> d_out (fp32)
    {
        int n8 = N_NODES * D_OUTF / 8;
        bn2_apply_kernel<<<(n8 + 255) / 256, 256, 0, stream>>>(x2, out, scale2, shift2, n8);
    }
}

// Round 4
// 275.435 us; speedup vs baseline: 1.2814x; 1.0209x over previous
//
#include <hip/hip_runtime.h>

#define N_NODES 50000
#define E_EDGES 800000
#define D_INF   128
#define D_HIDF  512
#define D_OUTF  128
#define SCAN_NB ((N_NODES + 255) / 256)   // 196
#define M1BLKS  ((N_NODES + 255) / 256)   // 196 row-blocks stats GEMM1 (256-row tiles)
#define FBLKS   ((N_NODES + 63) / 64)     // 782 row-blocks fused kernel (64-row tiles)
#define EQ      (E_EDGES / 4)             // 200,000 edges per ILP slot

// merged prep kernel block ranges
#define CAST_NB  3125                     // N*128/8 / 256
#define PREPW_NB 256                      // 65536 / 256 (each of W1, W2)
#define HIST_NB  ((EQ + 255) / 256)       // 782
#define PREP_ALL_NB (CAST_NB + 2 * PREPW_NB + HIST_NB)

typedef unsigned short u16;
typedef __attribute__((ext_vector_type(8))) short short8;
typedef __attribute__((ext_vector_type(4))) float floatx4;
typedef const __attribute__((address_space(1))) void gas_t;
typedef __attribute__((address_space(3))) void las_t;

__device__ __forceinline__ u16 f2bf(float f) {
    union { float f; unsigned u; } v; v.f = f;
    unsigned r = (v.u + 0x7fffu + ((v.u >> 16) & 1u)) >> 16;
    return (u16)r;
}
__device__ __forceinline__ float bf2f(u16 b) {
    union { unsigned u; float f; } v; v.u = ((unsigned)b) << 16; return v.f;
}

// ---------------- merged prep: cast v->bf16 | W1^T | W2^T | hist ----------------
__global__ __launch_bounds__(256) void prep_all_kernel(
        const float* __restrict__ v, const float* __restrict__ W1,
        const float* __restrict__ W2, const int* __restrict__ dst,
        u16* __restrict__ vbf, u16* __restrict__ W1t, u16* __restrict__ W2t,
        int* __restrict__ counts, int* __restrict__ pos) {
    int b = blockIdx.x;
    int tid = threadIdx.x;
    if (b < CAST_NB) {
        int i = b * 256 + tid;
        const float4 a = ((const float4*)v)[i * 2];
        const float4 c = ((const float4*)v)[i * 2 + 1];
        u16 o[8];
        o[0] = f2bf(a.x); o[1] = f2bf(a.y); o[2] = f2bf(a.z); o[3] = f2bf(a.w);
        o[4] = f2bf(c.x); o[5] = f2bf(c.y); o[6] = f2bf(c.z); o[7] = f2bf(c.w);
        ((float4*)vbf)[i] = *(const float4*)o;
    } else if (b < CAST_NB + PREPW_NB) {
        int idx = (b - CAST_NB) * 256 + tid;           // W1 [128][512]
        int k1 = idx >> 9, n1 = idx & 511;
        W1t[n1 * 128 + k1] = f2bf(W1[idx]);
    } else if (b < CAST_NB + 2 * PREPW_NB) {
        int idx = (b - CAST_NB - PREPW_NB) * 256 + tid; // W2 [512][128]
        int k2 = idx >> 7, n2 = idx & 127;
        W2t[n2 * 512 + k2] = f2bf(W2[idx]);
    } else {
        int t = (b - CAST_NB - 2 * PREPW_NB) * 256 + tid;
        if (t >= EQ) return;
        int d0 = dst[t];
        int d1 = dst[t + EQ];
        int d2 = dst[t + 2 * EQ];
        int d3 = dst[t + 3 * EQ];
        int p0 = atomicAdd(&counts[d0], 1);
        int p1 = atomicAdd(&counts[d1], 1);
        int p2 = atomicAdd(&counts[d2], 1);
        int p3 = atomicAdd(&counts[d3], 1);
        pos[t]          = p0;
        pos[t + EQ]     = p1;
        pos[t + 2 * EQ] = p2;
        pos[t + 3 * EQ] = p3;
    }
}

// ---------------- scan phase 1: per-block sums ----------------
__global__ __launch_bounds__(256) void reduce_kernel(const int* __restrict__ counts,
                                                     int* __restrict__ block_sums) {
    __shared__ int lsum[4];
    int tid = threadIdx.x;
    int gid = blockIdx.x * 256 + tid;
    int s = (gid < N_NODES) ? counts[gid] : 0;
#pragma unroll
    for (int off = 32; off; off >>= 1) s += __shfl_down(s, off);
    if ((tid & 63) == 0) lsum[tid >> 6] = s;
    __syncthreads();
    if (tid == 0) block_sums[blockIdx.x] = lsum[0] + lsum[1] + lsum[2] + lsum[3];
}

// ---------------- scan phase 2 (merged) ----------------
__global__ __launch_bounds__(256) void scan_final(const int* __restrict__ counts,
                                                  const int* __restrict__ block_sums,
                                                  int* __restrict__ row_start) {
    __shared__ int sh[256];
    __shared__ int bs[256];
    int tid = threadIdx.x;
    int gid = blockIdx.x * 256 + tid;
    sh[tid] = (gid < N_NODES) ? counts[gid] : 0;
    bs[tid] = (tid < SCAN_NB) ? block_sums[tid] : 0;
    __syncthreads();
    for (int off = 1; off < 256; off <<= 1) {
        int t1 = (tid >= off) ? sh[tid - off] : 0;
        int t2 = (tid >= off) ? bs[tid - off] : 0;
        __syncthreads();
        sh[tid] += t1;
        bs[tid] += t2;
        __syncthreads();
    }
    int boff = (blockIdx.x == 0) ? 0 : bs[blockIdx.x - 1];
    int excl = (tid == 0) ? 0 : sh[tid - 1];
    if (gid < N_NODES) row_start[gid] = boff + excl;
    if (gid == 0) row_start[N_NODES] = E_EDGES;
}

// ---------------- CSR fill — no atomics ----------------
__global__ void fill_kernel(const int* __restrict__ src, const int* __restrict__ dst,
                            const float* __restrict__ w, const int* __restrict__ pos,
                            const int* __restrict__ row_start,
                            int2* __restrict__ csr_ew) {
    int e = blockIdx.x * blockDim.x + threadIdx.x;
    if (e >= E_EDGES) return;
    int d = dst[e];
    int idx = row_start[d] + pos[e];
    int2 rec;
    rec.x = src[e];
    rec.y = __float_as_int(w[e]);
    csr_ew[idx] = rec;
}

// ---------------- gather: 16 lanes/node, 2-edge unroll ----------------
__global__ __launch_bounds__(256) void gather_kernel(const u16* __restrict__ vbf,
                                                     const int* __restrict__ row_start,
                                                     const int2* __restrict__ csr_ew,
                                                     const float* __restrict__ eps_p,
                                                     u16* __restrict__ vagg) {
    int node = blockIdx.x * 16 + (threadIdx.x >> 4);
    if (node >= N_NODES) return;
    int c8 = (threadIdx.x & 15) << 3;
    int beg = row_start[node];
    int end = row_start[node + 1];
    float a[8] = {};
    int j = beg;
    for (; j + 1 < end; j += 2) {
        int2 e0 = csr_ew[j];
        int2 e1 = csr_ew[j + 1];
        float w0 = __int_as_float(e0.y);
        float w1 = __int_as_float(e1.y);
        float4 r0 = *(const float4*)(vbf + (size_t)e0.x * D_INF + c8);
        float4 r1 = *(const float4*)(vbf + (size_t)e1.x * D_INF + c8);
        const u16* p0 = (const u16*)&r0;
        const u16* p1 = (const u16*)&r1;
#pragma unroll
        for (int t = 0; t < 8; ++t) a[t] += w0 * bf2f(p0[t]);
#pragma unroll
        for (int t = 0; t < 8; ++t) a[t] += w1 * bf2f(p1[t]);
    }
    if (j < end) {
        int2 e0 = csr_ew[j];
        float w0 = __int_as_float(e0.y);
        float4 r0 = *(const float4*)(vbf + (size_t)e0.x * D_INF + c8);
        const u16* p0 = (const u16*)&r0;
#pragma unroll
        for (int t = 0; t < 8; ++t) a[t] += w0 * bf2f(p0[t]);
    }
    float e = eps_p[0];
    float4 rn = *(const float4*)(vbf + (size_t)node * D_INF + c8);
    const u16* pn = (const u16*)&rn;
    u16 o[8];
#pragma unroll
    for (int t = 0; t < 8; ++t) o[t] = f2bf(a[t] + e * bf2f(pn[t]));
    *(float4*)(vagg + (size_t)node * D_INF + c8) = *(const float4*)o;
}

// ---------------- stats GEMM1: x1 partial sums/squares ONLY (no x1 write) ----------
// Verbatim R3 GEMM1 (256x128 tile, gload_lds staging, proven) minus the C epilogue.
// MFMA chain per output element is IDENTICAL to fused_mlp's recompute -> stats are
// exactly consistent with the recomputed x1.
__global__ __launch_bounds__(512) void stats_gemm1(
        const u16* __restrict__ A, const u16* __restrict__ Bt,
        const float* __restrict__ bias,
        float* __restrict__ psum, float* __restrict__ psq, int M) {
    __shared__ __align__(16) char smem[24576];
    u16* As = (u16*)smem;              // [256][32] u16, src slot-swz ^(row&3)
    u16* Bs = (u16*)(smem + 16384);    // [128][32] u16
    const int bm = blockIdx.y * 256;
    const int bn = blockIdx.x * 128;
    const int tid = threadIdx.x;
    const int wave = tid >> 6, lane = tid & 63;
    const int wr = wave >> 1, wc = wave & 1;
    const int wm = wr * 64, wn = wc * 64;
    const int lm = lane & 15, quad = lane >> 4;
    floatx4 acc[4][4] = {};
    for (int ks = 0; ks < 4; ++ks) {
        const int k0 = ks << 5;
        {
            const int sub = lane >> 2, s = lane & 3;
#pragma unroll
            for (int t = 0; t < 3; ++t) {
                int ch = wave * 3 + t;
                if (ch < 16) {
                    int row = ch * 16 + sub;
                    int grow = bm + row; if (grow > M - 1) grow = M - 1;
                    int ss = s ^ (row & 3);
                    __builtin_amdgcn_global_load_lds(
                        (gas_t*)(A + (size_t)grow * 128 + k0 + ss * 8),
                        (las_t*)(As + row * 32 + s * 8), 16, 0, 0);
                } else {
                    int row = (ch - 16) * 16 + sub;
                    int ss = s ^ (row & 3);
                    __builtin_amdgcn_global_load_lds(
                        (gas_t*)(Bt + (size_t)(bn + row) * 128 + k0 + ss * 8),
                        (las_t*)(Bs + row * 32 + s * 8), 16, 0, 0);
                }
            }
        }
        __syncthreads();
        short8 af[4], bfr[4];
#pragma unroll
        for (int i = 0; i < 4; ++i) {
            int row = wm + i * 16 + lm;
            af[i] = *(const short8*)&As[row * 32 + ((quad ^ (row & 3)) * 8)];
        }
#pragma unroll
        for (int j = 0; j < 4; ++j) {
            int row = wn + j * 16 + lm;
            bfr[j] = *(const short8*)&Bs[row * 32 + ((quad ^ (row & 3)) * 8)];
        }
#pragma unroll
        for (int i = 0; i < 4; ++i)
#pragma unroll
            for (int j = 0; j < 4; ++j)
                acc[i][j] = __builtin_amdgcn_mfma_f32_16x16x32_bf16(af[i], bfr[j], acc[i][j], 0, 0, 0);
        __syncthreads();
    }
    float* redS = (float*)smem;
    float* redQ = redS + 128;
    if (tid < 128) { redS[tid] = 0.f; redQ[tid] = 0.f; }
    __syncthreads();
#pragma unroll
    for (int j = 0; j < 4; ++j) {
        int cl = wn + j * 16 + lm;
        float bj = bias[bn + cl];
        float s = 0.f, q = 0.f;
#pragma unroll
        for (int i = 0; i < 4; ++i) {
            int row0 = bm + wm + i * 16 + quad * 4;
#pragma unroll
            for (int r = 0; r < 4; ++r)
                if (row0 + r < M) { float x = acc[i][j][r] + bj; s += x; q += x * x; }
        }
        s += __shfl_xor(s, 16); q += __shfl_xor(q, 16);
        s += __shfl_xor(s, 32); q += __shfl_xor(q, 32);
        if (quad == 0) { atomicAdd(&redS[cl], s); atomicAdd(&redQ[cl], q); }
    }
    __syncthreads();
    if (tid < 128) {
        psum[(size_t)blockIdx.y * 512 + bn + tid] = redS[tid];
        psq [(size_t)blockIdx.y * 512 + bn + tid] = redQ[tid];
    }
}

// ---------------- fused: GEMM1-recompute + BN1 + ReLU -> h(LDS) -> GEMM2 + BN2 partials ----
// 64 rows/block, 512 thr (8 waves = 2x4). LDS 80 KB -> 2 blocks/CU.
// R0 [0,16K):  vagg As [64][128]u16   -> W2s [128][64]u16
// R1 [16K,80K): W1s [512][64]u16      -> h   [64][512]u16
// All LDS tiles: 16B-slot XOR swizzle (slot ^= row&7 / &3) applied on BOTH the
// pre-swizzled global source and the ds_read side; LDS dest stays lane-linear.
__global__ __launch_bounds__(512, 4) void fused_mlp(
        const u16* __restrict__ vagg, const u16* __restrict__ W1t,
        const u16* __restrict__ W2t,
        const float* __restrict__ b1, const float* __restrict__ scale1,
        const float* __restrict__ shift1, const float* __restrict__ b2,
        u16* __restrict__ x2, float* __restrict__ psum, float* __restrict__ psq,
        int M) {
    __shared__ __align__(16) char smem[81920];
    u16* As  = (u16*)smem;
    u16* W1s = (u16*)(smem + 16384);
    u16* W2s = (u16*)smem;
    u16* hs  = (u16*)(smem + 16384);
    const int bm = blockIdx.x * 64;
    const int tid = threadIdx.x;
    const int wave = tid >> 6, lane = tid & 63;
    const int wr = wave >> 2, wc = wave & 3;     // 2 row x 4 col wave groups
    const int wm = wr * 32;
    const int wn1 = wc * 128;                    // GEMM1 col span 128
    const int wn2 = wc * 32;                     // GEMM2 col span 32
    const int lm = lane & 15, quad = lane >> 4;

    floatx4 acc1[2][8] = {};
    floatx4 acc2[2][2] = {};

    auto stage_w1 = [&](int win) {               // [512][64]u16 = 64 KB, 8 rounds
#pragma unroll
        for (int u = 0; u < 8; ++u) {
            int c = tid + u * 512;
            int col = c >> 3, s = c & 7;
            __builtin_amdgcn_global_load_lds(
                (gas_t*)(W1t + (size_t)col * 128 + win * 64 + ((s ^ (col & 7)) * 8)),
                (las_t*)(W1s + col * 64 + s * 8), 16, 0, 0);
        }
    };
    auto stage_w2 = [&](int win) {               // [128][64]u16 = 16 KB, 2 rounds
#pragma unroll
        for (int u = 0; u < 2; ++u) {
            int c = tid + u * 512;
            int n = c >> 3, s = c & 7;
            __builtin_amdgcn_global_load_lds(
                (gas_t*)(W2t + (size_t)n * 512 + win * 64 + ((s ^ (n & 7)) * 8)),
                (las_t*)(W2s + n * 64 + s * 8), 16, 0, 0);
        }
    };
    auto compute1 = [&](int ks) {                // ks in 0..3; W1s window = ks>>1
        short8 a[2], b[8];
#pragma unroll
        for (int i = 0; i < 2; ++i) {
            int row = wm + i * 16 + lm;
            a[i] = *(const short8*)&As[row * 128 + (((ks * 4 + quad) ^ (row & 7)) * 8)];
        }
#pragma unroll
        for (int j = 0; j < 8; ++j) {
            int col = wn1 + j * 16 + lm;
            b[j] = *(const short8*)&W1s[col * 64 + ((((ks & 1) * 4 + quad) ^ (col & 7)) * 8)];
        }
#pragma unroll
        for (int i = 0; i < 2; ++i)
#pragma unroll
            for (int j = 0; j < 8; ++j)
                acc1[i][j] = __builtin_amdgcn_mfma_f32_16x16x32_bf16(a[i], b[j], acc1[i][j], 0, 0, 0);
    };
    auto compute2 = [&](int ks) {                // ks in 0..15; W2s window = ks>>1
        short8 a[2], b[2];
#pragma unroll
        for (int i = 0; i < 2; ++i) {
            int row = wm + i * 16 + lm;
            a[i] = *(const short8*)&hs[row * 512 + (((ks * 4 + quad) ^ (row & 7)) * 8)];
        }
#pragma unroll
        for (int j = 0; j < 2; ++j) {
            int n = wn2 + j * 16 + lm;
            b[j] = *(const short8*)&W2s[n * 64 + ((((ks & 1) * 4 + quad) ^ (n & 7)) * 8)];
        }
#pragma unroll
        for (int i = 0; i < 2; ++i)
#pragma unroll
            for (int j = 0; j < 2; ++j)
                acc2[i][j] = __builtin_amdgcn_mfma_f32_16x16x32_bf16(a[i], b[j], acc2[i][j], 0, 0, 0);
    };

    // ---- stage vagg tile [64][128] + W1 window 0 ----
#pragma unroll
    for (int u = 0; u < 2; ++u) {
        int c = tid + u * 512;
        int row = c >> 4, s = c & 15;
        int grow = bm + row; if (grow > M - 1) grow = M - 1;
        __builtin_amdgcn_global_load_lds(
            (gas_t*)(vagg + (size_t)grow * 128 + ((s ^ (row & 7)) * 8)),
            (las_t*)(As + row * 128 + s * 8), 16, 0, 0);
    }
    stage_w1(0);
    __syncthreads();
    compute1(0); compute1(1);
    __syncthreads();
    stage_w1(1);
    __syncthreads();
    compute1(2); compute1(3);
    __syncthreads();                  // all reads of As / W1s done

    // ---- issue W2 window 0 early (into As region), then BN1+ReLU -> h ----
    stage_w2(0);
    {
        float hsc[8], hsh[8];
#pragma unroll
        for (int j = 0; j < 8; ++j) {
            int col = wn1 + j * 16 + lm;
            float sc = scale1[col];
            hsc[j] = sc;
            hsh[j] = shift1[col] + sc * b1[col];
        }
#pragma unroll
        for (int i = 0; i < 2; ++i)
#pragma unroll
            for (int j = 0; j < 8; ++j)
#pragma unroll
                for (int r = 0; r < 4; ++r) {
                    int row = wm + i * 16 + quad * 4 + r;
                    int col = wn1 + j * 16 + lm;
                    float hv = fmaxf(0.f, acc1[i][j][r] * hsc[j] + hsh[j]);
                    hs[row * 512 + (((col >> 3) ^ (row & 7)) * 8) + (col & 7)] = f2bf(hv);
                }
    }
    __syncthreads();                  // h visible + W2s(0) staged

    // ---- GEMM2: 8 windows x 2 ksteps ----
#pragma unroll
    for (int win = 0; win < 8; ++win) {
        compute2(win * 2); compute2(win * 2 + 1);
        __syncthreads();
        if (win < 7) { stage_w2(win + 1); __syncthreads(); }
    }

    // ---- BN2 partials ----
    float* redS = (float*)smem;
    float* redQ = redS + 128;
    if (tid < 128) { redS[tid] = 0.f; redQ[tid] = 0.f; }
    __syncthreads();
    float bj2[2];
#pragma unroll
    for (int j = 0; j < 2; ++j) {
        int cl = wn2 + j * 16 + lm;
        bj2[j] = b2[cl];
        float s = 0.f, q = 0.f;
#pragma unroll
        for (int i = 0; i < 2; ++i) {
            int row0 = bm + wm + i * 16 + quad * 4;
#pragma unroll
            for (int r = 0; r < 4; ++r)
                if (row0 + r < M) { float x = acc2[i][j][r] + bj2[j]; s += x; q += x * x; }
        }
        s += __shfl_xor(s, 16); q += __shfl_xor(q, 16);
        s += __shfl_xor(s, 32); q += __shfl_xor(q, 32);
        if (quad == 0) { atomicAdd(&redS[cl], s); atomicAdd(&redQ[cl], q); }
    }
    __syncthreads();
    if (tid < 128) {
        psum[(size_t)blockIdx.x * 128 + tid] = redS[tid];
        psq [(size_t)blockIdx.x * 128 + tid] = redQ[tid];
    }
    __syncthreads();                  // redS reads done before obuf overwrite

    // ---- coalesced bf16 x2 write via obuf [64][132] f32 ----
    float* obuf = (float*)smem;
#pragma unroll
    for (int i = 0; i < 2; ++i)
#pragma unroll
        for (int j = 0; j < 2; ++j)
#pragma unroll
            for (int r = 0; r < 4; ++r) {
                int row = wm + i * 16 + quad * 4 + r;
                int col = wn2 + j * 16 + lm;
                obuf[row * 132 + col] = acc2[i][j][r] + bj2[j];
            }
    __syncthreads();
    {
        int row = tid >> 3, seg = (tid & 7) * 16;
        int grow = bm + row;
        if (grow < M) {
            u16 ob[16];
#pragma unroll
            for (int t = 0; t < 4; ++t) {
                float4 f = *(float4*)&obuf[row * 132 + seg + t * 4];
                ob[t * 4 + 0] = f2bf(f.x);
                ob[t * 4 + 1] = f2bf(f.y);
                ob[t * 4 + 2] = f2bf(f.z);
                ob[t * 4 + 3] = f2bf(f.w);
            }
            u16* dp = x2 + (size_t)grow * 128 + seg;
            *(float4*)dp       = *(float4*)ob;
            *(float4*)(dp + 8) = *(float4*)(ob + 8);
        }
    }
}

// ---------------- BN finalize (parallel reduce of per-block partials) ----------------
__global__ __launch_bounds__(1024) void bn_finalize_kernel(
        const float* __restrict__ psum, const float* __restrict__ psq,
        const float* __restrict__ gamma, const float* __restrict__ beta,
        float* __restrict__ scale, float* __restrict__ shift,
        int nblocks, int Ncols, float inv_n) {
    __shared__ float shS[16][64];
    __shared__ float shQ[16][64];
    const int tx = threadIdx.x;
    const int ty = threadIdx.y;
    const int c = blockIdx.x * 64 + tx;
    float s = 0.f, q = 0.f;
    for (int b = ty; b < nblocks; b += 16) {
        s += psum[(size_t)b * Ncols + c];
        q += psq [(size_t)b * Ncols + c];
    }
    shS[ty][tx] = s;
    shQ[ty][tx] = q;
    __syncthreads();
    if (ty == 0) {
        float S = 0.f, Q = 0.f;
#pragma unroll
        for (int r = 0; r < 16; ++r) { S += shS[r][tx]; Q += shQ[r][tx]; }
        float m = S * inv_n;
        float var = Q * inv_n - m * m;
        float rs = rsqrtf(var + 1e-5f);
        float sc = gamma[c] * rs;
        scale[c] = sc;
        shift[c] = beta[c] - sc * m;
    }
}

// ---------------- BN2 apply + ReLU: x2 bf16 -> d_out fp32 ----------------
__global__ void bn2_apply_kernel(const u16* __restrict__ X, float* __restrict__ Y,
                                 const float* __restrict__ scale,
                                 const float* __restrict__ shift, int n8) {
    int i = blockIdx.x * blockDim.x + threadIdx.x;
    if (i >= n8) return;
    int c = (i & 15) << 3;
    float4 raw = ((const float4*)X)[i];
    const u16* xb = (const u16*)&raw;
    float4 sc0 = *(const float4*)(scale + c);
    float4 sc1 = *(const float4*)(scale + c + 4);
    float4 sh0 = *(const float4*)(shift + c);
    float4 sh1 = *(const float4*)(shift + c + 4);
    float4 y0, y1;
    y0.x = fmaxf(0.f, bf2f(xb[0]) * sc0.x + sh0.x);
    y0.y = fmaxf(0.f, bf2f(xb[1]) * sc0.y + sh0.y);
    y0.z = fmaxf(0.f, bf2f(xb[2]) * sc0.z + sh0.z);
    y0.w = fmaxf(0.f, bf2f(xb[3]) * sc0.w + sh0.w);
    y1.x = fmaxf(0.f, bf2f(xb[4]) * sc1.x + sh1.x);
    y1.y = fmaxf(0.f, bf2f(xb[5]) * sc1.y + sh1.y);
    y1.z = fmaxf(0.f, bf2f(xb[6]) * sc1.z + sh1.z);
    y1.w = fmaxf(0.f, bf2f(xb[7]) * sc1.w + sh1.w);
    ((float4*)Y)[i * 2]     = y0;
    ((float4*)Y)[i * 2 + 1] = y1;
}

extern "C" void kernel_launch(void* const* d_in, const int* in_sizes, int n_in,
                              void* d_out, int out_size, void* d_ws, size_t ws_size,
                              hipStream_t stream) {
    const float* v    = (const float*)d_in[0];
    const int* src    = (const int*)d_in[1];
    const int* dst    = (const int*)d_in[2];
    const float* ew   = (const float*)d_in[3];
    const float* eps  = (const float*)d_in[4];
    const float* W1   = (const float*)d_in[5];
    const float* b1   = (const float*)d_in[6];
    const float* g1   = (const float*)d_in[7];
    const float* be1  = (const float*)d_in[8];
    const float* W2   = (const float*)d_in[9];
    const float* b2   = (const float*)d_in[10];
    const float* g2   = (const float*)d_in[11];
    const float* be2  = (const float*)d_in[12];
    float* out = (float*)d_out;

    // ---- workspace layout (bytes) ----
    char* base = (char*)d_ws;
    u16* vbf  = (u16*)(base + 51200000ull);        // [N,128] bf16
    u16* vagg = (u16*)(base + 64000000ull);        // [N,128] bf16
    u16* x2   = (u16*)(base + 76800000ull);        // [N,128] bf16 raw pre-BN2
    u16* W1t  = (u16*)(base + 89600000ull);        // 512x128 bf16
    u16* W2t  = (u16*)(base + 89731072ull);        // 128x512 bf16
    float* psum   = (float*)(base + 89862144ull);  // [196][512] then [782][128]
    float* psq    = (float*)(base + 90663168ull);  // same
    float* scale1 = (float*)(base + 91464192ull);  // 512
    float* shift1 = scale1 + 512;
    float* scale2 = shift1 + 512;
    float* shift2 = scale2 + 128;
    int* counts     = (int*)(shift2 + 128);        // 50,000
    int* row_start  = counts + 50000;              // 50,001 (+pad 3)
    int* pos        = row_start + 50004;           // 800,000
    int2* csr_ew    = (int2*)(pos + 800000);       // 800,000 * 8 B
    int* block_sums = (int*)(csr_ew + 800000);     // 256

    hipMemsetAsync(counts, 0, (size_t)50000 * sizeof(int), stream);

    // merged prep (cast | W1^T | W2^T | hist) + CSR build + gather
    prep_all_kernel<<<PREP_ALL_NB, 256, 0, stream>>>(v, W1, W2, dst, vbf, W1t, W2t,
                                                     counts, pos);
    reduce_kernel<<<SCAN_NB, 256, 0, stream>>>(counts, block_sums);
    scan_final<<<SCAN_NB, 256, 0, stream>>>(counts, block_sums, row_start);
    fill_kernel<<<(E_EDGES + 255) / 256, 256, 0, stream>>>(src, dst, ew, pos, row_start, csr_ew);
    gather_kernel<<<(N_NODES + 15) / 16, 256, 0, stream>>>(vbf, row_start, csr_ew, eps, vagg);

    // pass 1: BN1 statistics only (no x1 materialization)
    {
        dim3 grid(D_HIDF / 128, M1BLKS);
        stats_gemm1<<<grid, 512, 0, stream>>>(vagg, W1t, b1, psum, psq, N_NODES);
    }
    bn_finalize_kernel<<<D_HIDF / 64, dim3(64, 16), 0, stream>>>(
        psum, psq, g1, be1, scale1, shift1, M1BLKS, D_HIDF, 1.0f / N_NODES);

    // pass 2: fused recompute-GEMM1 + BN1 + ReLU (h in LDS) + GEMM2 + BN2 partials
    fused_mlp<<<FBLKS, 512, 0, stream>>>(vagg, W1t, W2t, b1, scale1, shift1, b2,
                                         x2, psum, psq, N_NODES);
    bn_finalize_kernel<<<D_OUTF / 64, dim3(64, 16), 0, stream>>>(
        psum, psq, g2, be2, scale2, shift2, FBLKS, D_OUTF, 1.0f / N_NODES);

    // BN2 apply + ReLU: x2 (bf16) -> d_out (fp32)
    {
        int n8 = N_NODES * D_OUTF / 8;
        bn2_apply_kernel<<<(n8 + 255) / 256, 256, 0, stream>>>(x2, out, scale2, shift2, n8);
    }
}